// Round 7
// baseline (201.944 us; speedup 1.0000x reference)
//
#include <hip/hip_runtime.h>
#include <math.h>

#define BB 16
#define TQ 512
#define TK 1024
#define DD 512

typedef __bf16 bf16x8 __attribute__((ext_vector_type(8)));
typedef __bf16 bf16x4v __attribute__((ext_vector_type(4)));
typedef _Float16 f16x8 __attribute__((ext_vector_type(8)));
typedef _Float16 f16x4v __attribute__((ext_vector_type(4)));
typedef float f32x4 __attribute__((ext_vector_type(4)));

__device__ __forceinline__ unsigned short f16b(float x) {
    _Float16 h = (_Float16)x;
    return __builtin_bit_cast(unsigned short, h);
}

// async global(16B/lane) -> LDS (wave-uniform base + lane*16)
__device__ __forceinline__ void gload16(const void* g, void* l) {
    __builtin_amdgcn_global_load_lds(
        (const __attribute__((address_space(1))) unsigned int*)g,
        (__attribute__((address_space(3))) unsigned int*)l, 16, 0, 0);
}

// ============================================================================
// gemm16: NT GEMM on pre-converted fp16 operands, global_load_lds staging.
//  C[m][n] = sum_k A[m][k]*B[n][k]   OM=0: C fp32.  OM=2: fp16 -> D0.
// Tile TM x 128, 256 thr = 4 waves 2x2, wave tile (TM/2)x64, BK=64.
// LDS unpadded; 16B chunks XOR-swizzled within each 128B row.
// ============================================================================
template<int TM, int OM, bool BIAS, bool SCALE>
__global__ __launch_bounds__(256) void gemm16(
    const unsigned short* __restrict__ A0, const unsigned short* __restrict__ B0,
    float* __restrict__ C, unsigned short* __restrict__ D0,
    const float* __restrict__ bias, const float* __restrict__ scl,
    int N, int K, long sA, long sB, long sC)
{
    constexpr int WI = TM / 32;
    constexpr int IA = TM / 32;
    __shared__ unsigned short As0[TM * 64];
    __shared__ unsigned short Bs0[128 * 64];

    const int bz = blockIdx.z;
    const long oA = (long)bz * sA, oB = (long)bz * sB;
    const int m0 = blockIdx.y * TM;
    const int n0 = blockIdx.x * 128;
    const int tid = threadIdx.x, lane = tid & 63, wave = tid >> 6;
    const int wm0 = (wave >> 1) * (TM / 2);
    const int wn0 = (wave & 1) * 64;
    const int fm = lane & 15, fq = lane >> 4;

    f32x4 acc[WI][4];
    #pragma unroll
    for (int i = 0; i < WI; ++i)
        #pragma unroll
        for (int j = 0; j < 4; ++j) {
            f32x4 z = {0.f, 0.f, 0.f, 0.f};
            acc[i][j] = z;
        }

    for (int k0 = 0; k0 < K; k0 += 64) {
        #pragma unroll
        for (int t = 0; t < IA; ++t) {
            const int sb = (wave * IA + t) * 64;
            const int slot = sb + lane;
            const int row = slot >> 3;
            const int g = (slot & 7) ^ (row & 7);
            gload16(A0 + oA + (long)(m0 + row) * K + k0 + g * 8, &As0[sb * 8]);
        }
        #pragma unroll
        for (int t = 0; t < 4; ++t) {
            const int sb = (wave * 4 + t) * 64;
            const int slot = sb + lane;
            const int row = slot >> 3;
            const int g = (slot & 7) ^ (row & 7);
            gload16(B0 + oB + (long)(n0 + row) * K + k0 + g * 8, &Bs0[sb * 8]);
        }
        __syncthreads();

        #pragma unroll
        for (int s = 0; s < 2; ++s) {
            f16x8 fa[WI], fb[4];
            #pragma unroll
            for (int i = 0; i < WI; ++i) {
                const int row = wm0 + 16 * i + fm;
                const int slot = row * 8 + ((s * 4 + fq) ^ (row & 7));
                fa[i] = *(const f16x8*)&As0[slot * 8];
            }
            #pragma unroll
            for (int j = 0; j < 4; ++j) {
                const int row = wn0 + 16 * j + fm;
                const int slot = row * 8 + ((s * 4 + fq) ^ (row & 7));
                fb[j] = *(const f16x8*)&Bs0[slot * 8];
            }
            #pragma unroll
            for (int i = 0; i < WI; ++i)
                #pragma unroll
                for (int j = 0; j < 4; ++j)
                    acc[i][j] = __builtin_amdgcn_mfma_f32_16x16x32_f16(fa[i], fb[j], acc[i][j], 0, 0, 0);
        }
        __syncthreads();
    }

    const float sv = SCALE ? scl[0] : 1.0f;
    #pragma unroll
    for (int i = 0; i < WI; ++i) {
        #pragma unroll
        for (int j = 0; j < 4; ++j) {
            const int n = n0 + wn0 + 16 * j + fm;
            const float bv = BIAS ? bias[n] : 0.0f;
            #pragma unroll
            for (int r = 0; r < 4; ++r) {
                const int m = m0 + wm0 + 16 * i + fq * 4 + r;
                float v = acc[i][j][r] + bv;
                if (SCALE) v *= sv;
                const long o = (long)bz * sC + (long)m * N + n;
                if (OM == 0) C[o] = v;
                else         D0[o] = f16b(v);
            }
        }
    }
}

// ============================================================================
// scores_softmax: scores + masked softmax fused.
// Block = 16 q-rows x full K=1024 keys, 512 threads = 8 waves, wave owns 128
// keys (8 n-frags). Grid 512 blocks -> 2 blocks/CU, 16 waves/CU.
// aq tile (16x512, 16KB) staged once via global_load_lds (XOR-swizzled);
// k16 rows are wave-private -> direct b128 register loads (acc only 32 VGPRs,
// so loads pipeline). In-register softmax (16x16 C-layout: row=fq*4+r,
// col=fm), cross-wave reduce via LDS. Writes attn f32 + at16 f16.
// ============================================================================
__global__ __launch_bounds__(512) void scores_softmax(
    const unsigned short* __restrict__ aq16,  // [B*TQ][DD] f16
    const unsigned short* __restrict__ k16,   // [B][TK][DD] f16
    float* __restrict__ attn,                 // [B][TQ][TK]
    unsigned short* __restrict__ at16,        // [B*TQ][TK] f16
    const int* __restrict__ lens, const float* __restrict__ scl)
{
    __shared__ unsigned short As[16 * 64 * 8];   // 16 rows x 64 chunks(16B) = 16KB
    __shared__ float redm[8][16];
    __shared__ float reds[8][16];

    const int b  = blockIdx.z;
    const int m0 = blockIdx.x * 16;
    const int tid = threadIdx.x, lane = tid & 63, wave = tid >> 6;
    const int fm = lane & 15, fq = lane >> 4;
    const int len = lens[b];
    const float sc = scl[0];

    // ---- stage aq tile once (1024 chunks, 2 issues/wave)
    {
        const unsigned short* Ab = aq16 + ((long)b * TQ + m0) * DD;
        #pragma unroll
        for (int t = 0; t < 2; ++t) {
            const int sb = (wave * 2 + t) * 64;
            const int slot = sb + lane;
            const int r = slot >> 6;              // row 0..15
            const int g = (slot & 63) ^ (r & 7);  // fetch swizzled chunk
            gload16(Ab + (long)r * DD + g * 8, &As[sb * 8]);
        }
    }
    __syncthreads();

    // ---- scores: acc[jq] covers rows fq*4..+3, col wave*128 + jq*16 + fm
    f32x4 acc[8];
    #pragma unroll
    for (int j = 0; j < 8; ++j) {
        f32x4 z = {0.f, 0.f, 0.f, 0.f};
        acc[j] = z;
    }

    const unsigned short* Kb = k16 + ((long)b * TK + wave * 128) * DD;
    for (int dd = 0; dd < 8; ++dd) {             // d-chunks of 64
        f16x8 a[2];
        #pragma unroll
        for (int s = 0; s < 2; ++s)
            a[s] = *(const f16x8*)&As[(fm * 64 +
                      ((dd * 8 + s * 4 + fq) ^ (fm & 7))) * 8];
        #pragma unroll
        for (int jq = 0; jq < 8; ++jq) {
            f16x8 bv[2];
            #pragma unroll
            for (int s = 0; s < 2; ++s)
                bv[s] = *(const f16x8*)&Kb[(long)(jq * 16 + fm) * DD +
                                           dd * 64 + s * 32 + fq * 8];
            #pragma unroll
            for (int s = 0; s < 2; ++s)
                acc[jq] = __builtin_amdgcn_mfma_f32_16x16x32_f16(
                    a[s], bv[s], acc[jq], 0, 0, 0);
        }
    }

    // ---- masked softmax over 16 rows (in registers)
    float rmax[4] = {-INFINITY, -INFINITY, -INFINITY, -INFINITY};
    #pragma unroll
    for (int jq = 0; jq < 8; ++jq) {
        const int col = wave * 128 + jq * 16 + fm;
        const bool valid = col < len;
        #pragma unroll
        for (int r = 0; r < 4; ++r) {
            const float v = valid ? acc[jq][r] * sc : -INFINITY;
            acc[jq][r] = v;
            rmax[r] = fmaxf(rmax[r], v);
        }
    }
    #pragma unroll
    for (int off = 1; off < 16; off <<= 1)
        #pragma unroll
        for (int r = 0; r < 4; ++r)
            rmax[r] = fmaxf(rmax[r], __shfl_xor(rmax[r], off));
    if (fm == 0) {
        #pragma unroll
        for (int r = 0; r < 4; ++r) redm[wave][fq * 4 + r] = rmax[r];
    }
    __syncthreads();
    #pragma unroll
    for (int r = 0; r < 4; ++r) {
        const int row = fq * 4 + r;
        float m = redm[0][row];
        #pragma unroll
        for (int w = 1; w < 8; ++w) m = fmaxf(m, redm[w][row]);
        rmax[r] = m;
    }

    float rsum[4] = {0.f, 0.f, 0.f, 0.f};
    #pragma unroll
    for (int jq = 0; jq < 8; ++jq)
        #pragma unroll
        for (int r = 0; r < 4; ++r) {
            const float x = acc[jq][r];
            const float e = (x > -1e30f) ? __expf(x - rmax[r]) : 0.0f;
            acc[jq][r] = e;
            rsum[r] += e;
        }
    #pragma unroll
    for (int off = 1; off < 16; off <<= 1)
        #pragma unroll
        for (int r = 0; r < 4; ++r)
            rsum[r] += __shfl_xor(rsum[r], off);
    if (fm == 0) {
        #pragma unroll
        for (int r = 0; r < 4; ++r) reds[wave][fq * 4 + r] = rsum[r];
    }
    __syncthreads();
    #pragma unroll
    for (int r = 0; r < 4; ++r) {
        const int row = fq * 4 + r;
        float s = reds[0][row];
        #pragma unroll
        for (int w = 1; w < 8; ++w) s += reds[w][row];
        const float inv = 1.0f / s;
        #pragma unroll
        for (int jq = 0; jq < 8; ++jq) acc[jq][r] *= inv;
    }

    // ---- write attn (f32 output) + at16 (f16 for context GEMM)
    float* arow = attn + ((long)b * TQ + m0) * TK;
    unsigned short* prow = at16 + ((long)b * TQ + m0) * TK;
    #pragma unroll
    for (int jq = 0; jq < 8; ++jq) {
        const int col = wave * 128 + jq * 16 + fm;
        #pragma unroll
        for (int r = 0; r < 4; ++r) {
            const int row = fq * 4 + r;
            const float p = acc[jq][r];
            arow[(long)row * TK + col] = p;
            prow[(long)row * TK + col] = f16b(p);
        }
    }
}

// query + Wq -> fp16 (float4 per thread)
__global__ __launch_bounds__(256) void cvt_qw_kernel(
    const float* __restrict__ q, const float* __restrict__ w,
    unsigned short* __restrict__ q16, unsigned short* __restrict__ w16,
    int nq4, int nw4)
{
    const int t = blockIdx.x * 256 + threadIdx.x;
    const float* s;
    unsigned short* d;
    if (t < nq4)            { s = q + (long)t * 4;         d = q16 + (long)t * 4; }
    else if (t < nq4 + nw4) { s = w + (long)(t - nq4) * 4; d = w16 + (long)(t - nq4) * 4; }
    else return;
    const float4 v = *(const float4*)s;
    f16x4v o = {(_Float16)v.x, (_Float16)v.y, (_Float16)v.z, (_Float16)v.w};
    *(f16x4v*)d = o;
}

// keys -> fp16 row-major [b][k][d] + fp16 transposed [b][d][k], 64x64 tiles
__global__ __launch_bounds__(256) void cvt_keys_kernel(
    const float* __restrict__ keys, unsigned short* __restrict__ k16,
    unsigned short* __restrict__ kT)
{
    __shared__ unsigned short T[64][72];
    const int b = blockIdx.z, kt = blockIdx.x, dt = blockIdx.y;
    const int tid = threadIdx.x;
    const float* src = keys + ((long)b * TK + (long)kt * 64) * DD + dt * 64;

    #pragma unroll
    for (int i = 0; i < 4; ++i) {
        const int slot = tid + i * 256;
        const int r  = slot >> 4;
        const int c4 = (slot & 15) * 4;
        const float4 v = *(const float4*)(src + (long)r * DD + c4);
        const unsigned short h0 = f16b(v.x), h1 = f16b(v.y),
                             h2 = f16b(v.z), h3 = f16b(v.w);
        *(ushort4*)&k16[((long)b * TK + kt * 64 + r) * DD + dt * 64 + c4] =
            make_ushort4(h0, h1, h2, h3);
        T[c4 + 0][r] = h0;
        T[c4 + 1][r] = h1;
        T[c4 + 2][r] = h2;
        T[c4 + 3][r] = h3;
    }
    __syncthreads();
    #pragma unroll
    for (int i = 0; i < 4; ++i) {
        const int slot = tid + i * 256;
        const int c  = slot >> 4;
        const int r4 = (slot & 15) * 4;
        const ushort4 o4 = *(const ushort4*)&T[c][r4];
        *(ushort4*)&kT[((long)b * DD + dt * 64 + c) * TK + kt * 64 + r4] = o4;
    }
}

// ============================================================================
// FALLBACK PATH: fp32-input MFMA GEMM with in-loop conversion (round-3 proven).
// ============================================================================
template<int TM, bool SPLIT, bool BT, bool BIAS, bool SCALE>
__global__ __launch_bounds__(256) void mfma_gemm(
    const float* __restrict__ A, const float* __restrict__ Bm,
    float* __restrict__ C, const float* __restrict__ bias,
    const float* __restrict__ scl,
    int N, int K, long sA, long sB, long sC)
{
    constexpr int WI  = TM / 32;
    constexpr int LDT = 40;
    __shared__ unsigned short As_hi[TM * LDT];
    __shared__ unsigned short Bs_hi[128 * LDT];
    __shared__ unsigned short As_lo[SPLIT ? TM * LDT : 8];
    __shared__ unsigned short Bs_lo[SPLIT ? 128 * LDT : 8];

    const int bz = blockIdx.z;
    A  += (long)bz * sA;
    Bm += (long)bz * sB;
    C  += (long)bz * sC;

    const int m0 = blockIdx.y * TM;
    const int n0 = blockIdx.x * 128;
    const int tid  = threadIdx.x;
    const int lane = tid & 63;
    const int wave = tid >> 6;
    const int wm0 = (wave >> 1) * (TM / 2);
    const int wn0 = (wave & 1) * 64;
    const int fm = lane & 15;
    const int fq = lane >> 4;

    f32x4 acc[WI][4];
    #pragma unroll
    for (int i = 0; i < WI; ++i)
        #pragma unroll
        for (int j = 0; j < 4; ++j) {
            f32x4 z = {0.f, 0.f, 0.f, 0.f};
            acc[i][j] = z;
        }

    for (int k0 = 0; k0 < K; k0 += 32) {
        #pragma unroll
        for (int i = 0; i < WI; ++i) {
            const int s   = tid + i * 256;
            const int row = s >> 3;
            const int c4  = (s & 7) << 2;
            const float4 v = *(const float4*)(A + (long)(m0 + row) * K + k0 + c4);
            if (SPLIT) {
                const __bf16 h0 = (__bf16)v.x, h1 = (__bf16)v.y,
                             h2 = (__bf16)v.z, h3 = (__bf16)v.w;
                bf16x4v hv = {h0, h1, h2, h3};
                *(bf16x4v*)&As_hi[row * LDT + c4] = hv;
                bf16x4v lv = {(__bf16)(v.x - (float)h0), (__bf16)(v.y - (float)h1),
                              (__bf16)(v.z - (float)h2), (__bf16)(v.w - (float)h3)};
                *(bf16x4v*)&As_lo[row * LDT + c4] = lv;
            } else {
                f16x4v hv = {(_Float16)v.x, (_Float16)v.y, (_Float16)v.z, (_Float16)v.w};
                *(f16x4v*)&As_hi[row * LDT + c4] = hv;
            }
        }
        if (BT) {
            #pragma unroll
            for (int i = 0; i < 4; ++i) {
                const int s   = tid + i * 256;
                const int row = s >> 3;
                const int c4  = (s & 7) << 2;
                const float4 v = *(const float4*)(Bm + (long)(n0 + row) * K + k0 + c4);
                if (SPLIT) {
                    const __bf16 h0 = (__bf16)v.x, h1 = (__bf16)v.y,
                                 h2 = (__bf16)v.z, h3 = (__bf16)v.w;
                    bf16x4v hv = {h0, h1, h2, h3};
                    *(bf16x4v*)&Bs_hi[row * LDT + c4] = hv;
                    bf16x4v lv = {(__bf16)(v.x - (float)h0), (__bf16)(v.y - (float)h1),
                                  (__bf16)(v.z - (float)h2), (__bf16)(v.w - (float)h3)};
                    *(bf16x4v*)&Bs_lo[row * LDT + c4] = lv;
                } else {
                    f16x4v hv = {(_Float16)v.x, (_Float16)v.y, (_Float16)v.z, (_Float16)v.w};
                    *(f16x4v*)&Bs_hi[row * LDT + c4] = hv;
                }
            }
        } else {
            const int n  = tid & 127;
            const int kh2 = tid >> 7;
            const float* src = Bm + (long)(k0 + kh2 * 16) * N + n0 + n;
            float xs[16];
            #pragma unroll
            for (int j2 = 0; j2 < 16; ++j2) xs[j2] = src[(long)j2 * N];
            #pragma unroll
            for (int w2 = 0; w2 < 4; ++w2) {
                if (SPLIT) {
                    const __bf16 h0 = (__bf16)xs[w2*4+0], h1 = (__bf16)xs[w2*4+1],
                                 h2 = (__bf16)xs[w2*4+2], h3 = (__bf16)xs[w2*4+3];
                    bf16x4v hv = {h0, h1, h2, h3};
                    *(bf16x4v*)&Bs_hi[n * LDT + kh2 * 16 + w2 * 4] = hv;
                    bf16x4v lv = {(__bf16)(xs[w2*4+0] - (float)h0),
                                  (__bf16)(xs[w2*4+1] - (float)h1),
                                  (__bf16)(xs[w2*4+2] - (float)h2),
                                  (__bf16)(xs[w2*4+3] - (float)h3)};
                    *(bf16x4v*)&Bs_lo[n * LDT + kh2 * 16 + w2 * 4] = lv;
                } else {
                    f16x4v hv = {(_Float16)xs[w2*4+0], (_Float16)xs[w2*4+1],
                                 (_Float16)xs[w2*4+2], (_Float16)xs[w2*4+3]};
                    *(f16x4v*)&Bs_hi[n * LDT + kh2 * 16 + w2 * 4] = hv;
                }
            }
        }
        __syncthreads();

        if (SPLIT) {
            bf16x8 ah[WI], al[WI], bh[4], bl[4];
            #pragma unroll
            for (int i = 0; i < WI; ++i) {
                const int ra = (wm0 + 16 * i + fm) * LDT + fq * 8;
                ah[i] = *(const bf16x8*)&As_hi[ra];
                al[i] = *(const bf16x8*)&As_lo[ra];
            }
            #pragma unroll
            for (int j = 0; j < 4; ++j) {
                const int rb = (wn0 + 16 * j + fm) * LDT + fq * 8;
                bh[j] = *(const bf16x8*)&Bs_hi[rb];
                bl[j] = *(const bf16x8*)&Bs_lo[rb];
            }
            #pragma unroll
            for (int i = 0; i < WI; ++i)
                #pragma unroll
                for (int j = 0; j < 4; ++j) {
                    acc[i][j] = __builtin_amdgcn_mfma_f32_16x16x32_bf16(ah[i], bh[j], acc[i][j], 0, 0, 0);
                    acc[i][j] = __builtin_amdgcn_mfma_f32_16x16x32_bf16(ah[i], bl[j], acc[i][j], 0, 0, 0);
                    acc[i][j] = __builtin_amdgcn_mfma_f32_16x16x32_bf16(al[i], bh[j], acc[i][j], 0, 0, 0);
                }
        } else {
            f16x8 fa[WI], fb[4];
            #pragma unroll
            for (int i = 0; i < WI; ++i)
                fa[i] = *(const f16x8*)&As_hi[(wm0 + 16 * i + fm) * LDT + fq * 8];
            #pragma unroll
            for (int j = 0; j < 4; ++j)
                fb[j] = *(const f16x8*)&Bs_hi[(wn0 + 16 * j + fm) * LDT + fq * 8];
            #pragma unroll
            for (int i = 0; i < WI; ++i)
                #pragma unroll
                for (int j = 0; j < 4; ++j)
                    acc[i][j] = __builtin_amdgcn_mfma_f32_16x16x32_f16(fa[i], fb[j], acc[i][j], 0, 0, 0);
        }
        __syncthreads();
    }

    const float s = SCALE ? scl[0] : 1.0f;
    #pragma unroll
    for (int i = 0; i < WI; ++i) {
        #pragma unroll
        for (int j = 0; j < 4; ++j) {
            const int n = n0 + wn0 + 16 * j + fm;
            float bv = BIAS ? bias[n] : 0.0f;
            #pragma unroll
            for (int r = 0; r < 4; ++r) {
                const int m = m0 + wm0 + 16 * i + fq * 4 + r;
                float v = acc[i][j][r] + bv;
                if (SCALE) v *= s;
                C[(long)m * N + n] = v;
            }
        }
    }
}

// Masked softmax (fallback path), one block per (b,q) row.
__global__ __launch_bounds__(256) void softmax_kernel(
    float* __restrict__ attn, const int* __restrict__ lens)
{
    const int row = blockIdx.x;
    const int b   = row >> 9;
    const int len = lens[b];
    float* p = attn + (long)row * TK;

    const int tid  = threadIdx.x;
    const int lane = tid & 63;
    const int wave = tid >> 6;
    const int k0   = tid * 4;

    const float4 v = *(const float4*)(p + k0);
    float x[4] = {v.x, v.y, v.z, v.w};
    float mx = -INFINITY;
    #pragma unroll
    for (int i = 0; i < 4; ++i) {
        if (k0 + i < len) mx = fmaxf(mx, x[i]);
        else x[i] = -INFINITY;
    }
    #pragma unroll
    for (int off = 32; off; off >>= 1) mx = fmaxf(mx, __shfl_xor(mx, off, 64));

    __shared__ float red[8];
    if (lane == 0) red[wave] = mx;
    __syncthreads();
    mx = fmaxf(fmaxf(red[0], red[1]), fmaxf(red[2], red[3]));

    float e[4];
    float sum = 0.0f;
    #pragma unroll
    for (int i = 0; i < 4; ++i) {
        e[i] = (x[i] > -INFINITY) ? __expf(x[i] - mx) : 0.0f;
        sum += e[i];
    }
    #pragma unroll
    for (int off = 32; off; off >>= 1) sum += __shfl_xor(sum, off, 64);
    if (lane == 0) red[4 + wave] = sum;
    __syncthreads();
    sum = red[4] + red[5] + red[6] + red[7];

    const float inv = 1.0f / sum;
    float4 o = {e[0] * inv, e[1] * inv, e[2] * inv, e[3] * inv};
    *(float4*)(p + k0) = o;
}

extern "C" void kernel_launch(void* const* d_in, const int* in_sizes, int n_in,
                              void* d_out, int out_size, void* d_ws, size_t ws_size,
                              hipStream_t stream) {
    (void)in_sizes; (void)n_in; (void)out_size;

    const float* query = (const float*)d_in[0];
    const float* keys  = (const float*)d_in[1];
    const int*   lens  = (const int*)d_in[2];
    const float* Wq    = (const float*)d_in[3];
    const float* bq    = (const float*)d_in[4];
    const float* scale = (const float*)d_in[5];

    float* out  = (float*)d_out;
    float* ctx  = out;                               // B*TQ*D
    float* attn = out + (size_t)BB * TQ * DD;        // B*TQ*TK

    const size_t NQ  = (size_t)BB * TQ * DD;   // 4,194,304
    const size_t NW  = (size_t)DD * DD;        //   262,144
    const size_t NK  = (size_t)BB * TK * DD;   // 8,388,608
    const size_t NAT = (size_t)BB * TQ * TK;   // 8,388,608
    const size_t REQ = (2 * NQ + NW + 2 * NK + NAT) * 2;  // ~68 MB

    if (ws_size >= REQ) {
        unsigned short* w = (unsigned short*)d_ws;
        unsigned short* q16  = w;               w += NQ;
        unsigned short* w16  = w;               w += NW;
        unsigned short* aq16 = w;               w += NQ;
        unsigned short* k16  = w;               w += NK;
        unsigned short* kT   = w;               w += NK;
        unsigned short* at16 = w;

        // 0a) query+Wq -> fp16
        const int nq4 = (int)(NQ / 4), nw4 = (int)(NW / 4);
        cvt_qw_kernel<<<(nq4 + nw4 + 255) / 256, 256, 0, stream>>>(
            query, Wq, q16, w16, nq4, nw4);
        // 0b) keys -> fp16 + fp16 transposed
        cvt_keys_kernel<<<dim3(TK / 64, DD / 64, BB), 256, 0, stream>>>(
            keys, k16, kT);

        // 1) aq16 = f16gemm(query,Wq) + bq   M=8192 N=512 K=512
        gemm16<64, 2, true, false>
            <<<dim3(DD / 128, (BB * TQ) / 64, 1), 256, 0, stream>>>(
            q16, w16, nullptr, aq16, bq, nullptr, DD, DD, 0, 0, 0);

        // 2) fused scores + masked softmax -> attn (f32) + at16 (f16)
        scores_softmax<<<dim3(TQ / 16, 1, BB), 512, 0, stream>>>(
            aq16, k16, attn, at16, lens, scale);

        // 3) context = f16gemm(attn16, keysT)  M=512 N=512 K=1024 per batch
        gemm16<64, 0, false, false>
            <<<dim3(DD / 128, TQ / 64, BB), 256, 0, stream>>>(
            at16, kT, ctx, nullptr, nullptr, nullptr,
            DD, TK, (long)TQ * TK, (long)DD * TK, (long)TQ * DD);
    } else {
        // fallback: round-3 path (in-loop conversion)
        float* aq = ctx;
        mfma_gemm<64, false, true, true, false>
            <<<dim3(DD / 128, (BB * TQ) / 64, 1), 256, 0, stream>>>(
            query, Wq, aq, bq, nullptr, DD, DD, 0, 0, 0);
        mfma_gemm<128, true, true, false, true>
            <<<dim3(TK / 128, TQ / 128, BB), 256, 0, stream>>>(
            aq, keys, attn, nullptr, scale, TK, DD,
            (long)TQ * DD, (long)TK * DD, (long)TQ * TK);
        softmax_kernel<<<BB * TQ, 256, 0, stream>>>(attn, lens);
        mfma_gemm<64, false, false, false, false>
            <<<dim3(DD / 128, TQ / 64, BB), 256, 0, stream>>>(
            attn, keys, ctx, nullptr, nullptr, DD, TK,
            (long)TQ * TK, (long)TK * DD, (long)TQ * DD);
    }
}

// Round 8
// 164.186 us; speedup vs baseline: 1.2300x; 1.2300x over previous
//
#include <hip/hip_runtime.h>
#include <math.h>

#define BB 16
#define TQ 512
#define TK 1024
#define DD 512

typedef __bf16 bf16x8 __attribute__((ext_vector_type(8)));
typedef __bf16 bf16x4v __attribute__((ext_vector_type(4)));
typedef _Float16 f16x8 __attribute__((ext_vector_type(8)));
typedef _Float16 f16x4v __attribute__((ext_vector_type(4)));
typedef float f32x4 __attribute__((ext_vector_type(4)));

__device__ __forceinline__ unsigned short f16b(float x) {
    _Float16 h = (_Float16)x;
    return __builtin_bit_cast(unsigned short, h);
}

// async global(16B/lane) -> LDS (wave-uniform base + lane*16)
__device__ __forceinline__ void gload16(const void* g, void* l) {
    __builtin_amdgcn_global_load_lds(
        (const __attribute__((address_space(1))) unsigned int*)g,
        (__attribute__((address_space(3))) unsigned int*)l, 16, 0, 0);
}

// ============================================================================
// gemm16: NT GEMM on pre-converted fp16 operands, global_load_lds staging.
//  C[m][n] = sum_k A[m][k]*B[n][k]   OM=0: C fp32.  OM=2: fp16 -> D0.
// Tile TM x 128, 256 thr = 4 waves 2x2, wave tile (TM/2)x64, BK=64.
// LDS unpadded; 16B chunks XOR-swizzled within each 128B row.
// SWZ_NX>0: 1-D grid of 512 blocks decoded so XCD k hosts batches {2k,2k+1}
//   (xcd = L&7 under round-robin dispatch; slot-major within xcd). Keeps each
//   XCD's L2 working set to 2 batches -> ~2-4 MB, fits the 4 MB XCD L2.
//   Requires grid==512, 16 batches, 32 tiles/batch, n-tiles == SWZ_NX.
// ============================================================================
template<int TM, int OM, bool BIAS, bool SCALE, int SWZ_NX>
__global__ __launch_bounds__(256) void gemm16(
    const unsigned short* __restrict__ A0, const unsigned short* __restrict__ B0,
    float* __restrict__ C, unsigned short* __restrict__ D0,
    const float* __restrict__ bias, const float* __restrict__ scl,
    int N, int K, long sA, long sB, long sC)
{
    constexpr int WI = TM / 32;
    constexpr int IA = TM / 32;
    __shared__ unsigned short As0[TM * 64];
    __shared__ unsigned short Bs0[128 * 64];

    int bz, m0, n0;
    if (SWZ_NX > 0) {
        const int L = blockIdx.x;          // 0..511
        const int xcd = L & 7;
        const int s   = L >> 3;            // 0..63 slot within xcd
        bz = xcd * 2 + (s >> 5);           // 2 batches per xcd
        const int t = s & 31;              // 32 tiles per batch
        n0 = (t % SWZ_NX) * 128;
        m0 = (t / SWZ_NX) * TM;
    } else {
        bz = blockIdx.z;
        m0 = blockIdx.y * TM;
        n0 = blockIdx.x * 128;
    }

    const long oA = (long)bz * sA, oB = (long)bz * sB;
    const int tid = threadIdx.x, lane = tid & 63, wave = tid >> 6;
    const int wm0 = (wave >> 1) * (TM / 2);
    const int wn0 = (wave & 1) * 64;
    const int fm = lane & 15, fq = lane >> 4;

    f32x4 acc[WI][4];
    #pragma unroll
    for (int i = 0; i < WI; ++i)
        #pragma unroll
        for (int j = 0; j < 4; ++j) {
            f32x4 z = {0.f, 0.f, 0.f, 0.f};
            acc[i][j] = z;
        }

    for (int k0 = 0; k0 < K; k0 += 64) {
        #pragma unroll
        for (int t = 0; t < IA; ++t) {
            const int sb = (wave * IA + t) * 64;
            const int slot = sb + lane;
            const int row = slot >> 3;
            const int g = (slot & 7) ^ (row & 7);
            gload16(A0 + oA + (long)(m0 + row) * K + k0 + g * 8, &As0[sb * 8]);
        }
        #pragma unroll
        for (int t = 0; t < 4; ++t) {
            const int sb = (wave * 4 + t) * 64;
            const int slot = sb + lane;
            const int row = slot >> 3;
            const int g = (slot & 7) ^ (row & 7);
            gload16(B0 + oB + (long)(n0 + row) * K + k0 + g * 8, &Bs0[sb * 8]);
        }
        __syncthreads();

        #pragma unroll
        for (int s = 0; s < 2; ++s) {
            f16x8 fa[WI], fb[4];
            #pragma unroll
            for (int i = 0; i < WI; ++i) {
                const int row = wm0 + 16 * i + fm;
                const int slot = row * 8 + ((s * 4 + fq) ^ (row & 7));
                fa[i] = *(const f16x8*)&As0[slot * 8];
            }
            #pragma unroll
            for (int j = 0; j < 4; ++j) {
                const int row = wn0 + 16 * j + fm;
                const int slot = row * 8 + ((s * 4 + fq) ^ (row & 7));
                fb[j] = *(const f16x8*)&Bs0[slot * 8];
            }
            #pragma unroll
            for (int i = 0; i < WI; ++i)
                #pragma unroll
                for (int j = 0; j < 4; ++j)
                    acc[i][j] = __builtin_amdgcn_mfma_f32_16x16x32_f16(fa[i], fb[j], acc[i][j], 0, 0, 0);
        }
        __syncthreads();
    }

    const float sv = SCALE ? scl[0] : 1.0f;
    #pragma unroll
    for (int i = 0; i < WI; ++i) {
        #pragma unroll
        for (int j = 0; j < 4; ++j) {
            const int n = n0 + wn0 + 16 * j + fm;
            const float bv = BIAS ? bias[n] : 0.0f;
            #pragma unroll
            for (int r = 0; r < 4; ++r) {
                const int m = m0 + wm0 + 16 * i + fq * 4 + r;
                float v = acc[i][j][r] + bv;
                if (SCALE) v *= sv;
                const long o = (long)bz * sC + (long)m * N + n;
                if (OM == 0) C[o] = v;
                else         D0[o] = f16b(v);
            }
        }
    }
}

// query + Wq -> fp16 (float4 per thread)
__global__ __launch_bounds__(256) void cvt_qw_kernel(
    const float* __restrict__ q, const float* __restrict__ w,
    unsigned short* __restrict__ q16, unsigned short* __restrict__ w16,
    int nq4, int nw4)
{
    const int t = blockIdx.x * 256 + threadIdx.x;
    const float* s;
    unsigned short* d;
    if (t < nq4)            { s = q + (long)t * 4;         d = q16 + (long)t * 4; }
    else if (t < nq4 + nw4) { s = w + (long)(t - nq4) * 4; d = w16 + (long)(t - nq4) * 4; }
    else return;
    const float4 v = *(const float4*)s;
    f16x4v o = {(_Float16)v.x, (_Float16)v.y, (_Float16)v.z, (_Float16)v.w};
    *(f16x4v*)d = o;
}

// keys -> fp16 row-major [b][k][d] + fp16 transposed [b][d][k], 64x64 tiles
__global__ __launch_bounds__(256) void cvt_keys_kernel(
    const float* __restrict__ keys, unsigned short* __restrict__ k16,
    unsigned short* __restrict__ kT)
{
    __shared__ unsigned short T[64][72];
    const int b = blockIdx.z, kt = blockIdx.x, dt = blockIdx.y;
    const int tid = threadIdx.x;
    const float* src = keys + ((long)b * TK + (long)kt * 64) * DD + dt * 64;

    #pragma unroll
    for (int i = 0; i < 4; ++i) {
        const int slot = tid + i * 256;
        const int r  = slot >> 4;
        const int c4 = (slot & 15) * 4;
        const float4 v = *(const float4*)(src + (long)r * DD + c4);
        const unsigned short h0 = f16b(v.x), h1 = f16b(v.y),
                             h2 = f16b(v.z), h3 = f16b(v.w);
        *(ushort4*)&k16[((long)b * TK + kt * 64 + r) * DD + dt * 64 + c4] =
            make_ushort4(h0, h1, h2, h3);
        T[c4 + 0][r] = h0;
        T[c4 + 1][r] = h1;
        T[c4 + 2][r] = h2;
        T[c4 + 3][r] = h3;
    }
    __syncthreads();
    #pragma unroll
    for (int i = 0; i < 4; ++i) {
        const int slot = tid + i * 256;
        const int c  = slot >> 4;
        const int r4 = (slot & 15) * 4;
        const ushort4 o4 = *(const ushort4*)&T[c][r4];
        *(ushort4*)&kT[((long)b * DD + dt * 64 + c) * TK + kt * 64 + r4] = o4;
    }
}

// Masked softmax, one block per (b,q) row; writes attn f32 + at16 f16.
__global__ __launch_bounds__(256) void softmax_kernel(
    float* __restrict__ attn, unsigned short* __restrict__ attn16,
    const int* __restrict__ lens)
{
    const int row = blockIdx.x;
    const int b   = row >> 9;            // row / TQ (TQ=512)
    const int len = lens[b];
    float* p = attn + (long)row * TK;

    const int tid  = threadIdx.x;
    const int lane = tid & 63;
    const int wave = tid >> 6;
    const int k0   = tid * 4;

    const float4 v = *(const float4*)(p + k0);
    float x[4] = {v.x, v.y, v.z, v.w};
    float mx = -INFINITY;
    #pragma unroll
    for (int i = 0; i < 4; ++i) {
        if (k0 + i < len) mx = fmaxf(mx, x[i]);
        else x[i] = -INFINITY;
    }
    #pragma unroll
    for (int off = 32; off; off >>= 1) mx = fmaxf(mx, __shfl_xor(mx, off, 64));

    __shared__ float red[8];
    if (lane == 0) red[wave] = mx;
    __syncthreads();
    mx = fmaxf(fmaxf(red[0], red[1]), fmaxf(red[2], red[3]));

    float e[4];
    float sum = 0.0f;
    #pragma unroll
    for (int i = 0; i < 4; ++i) {
        e[i] = (x[i] > -INFINITY) ? __expf(x[i] - mx) : 0.0f;
        sum += e[i];
    }
    #pragma unroll
    for (int off = 32; off; off >>= 1) sum += __shfl_xor(sum, off, 64);
    if (lane == 0) red[4 + wave] = sum;
    __syncthreads();
    sum = red[4] + red[5] + red[6] + red[7];

    const float inv = 1.0f / sum;
    const float o0 = e[0] * inv, o1 = e[1] * inv, o2 = e[2] * inv, o3 = e[3] * inv;
    float4 o = {o0, o1, o2, o3};
    *(float4*)(p + k0) = o;
    if (attn16) {
        f16x4v o16 = {(_Float16)o0, (_Float16)o1, (_Float16)o2, (_Float16)o3};
        *(f16x4v*)&attn16[(long)row * TK + k0] = o16;
    }
}

// ============================================================================
// FALLBACK PATH: fp32-input MFMA GEMM with in-loop conversion (round-3 proven).
// ============================================================================
template<int TM, bool SPLIT, bool BT, bool BIAS, bool SCALE>
__global__ __launch_bounds__(256) void mfma_gemm(
    const float* __restrict__ A, const float* __restrict__ Bm,
    float* __restrict__ C, const float* __restrict__ bias,
    const float* __restrict__ scl,
    int N, int K, long sA, long sB, long sC)
{
    constexpr int WI  = TM / 32;
    constexpr int LDT = 40;
    __shared__ unsigned short As_hi[TM * LDT];
    __shared__ unsigned short Bs_hi[128 * LDT];
    __shared__ unsigned short As_lo[SPLIT ? TM * LDT : 8];
    __shared__ unsigned short Bs_lo[SPLIT ? 128 * LDT : 8];

    const int bz = blockIdx.z;
    A  += (long)bz * sA;
    Bm += (long)bz * sB;
    C  += (long)bz * sC;

    const int m0 = blockIdx.y * TM;
    const int n0 = blockIdx.x * 128;
    const int tid  = threadIdx.x;
    const int lane = tid & 63;
    const int wave = tid >> 6;
    const int wm0 = (wave >> 1) * (TM / 2);
    const int wn0 = (wave & 1) * 64;
    const int fm = lane & 15;
    const int fq = lane >> 4;

    f32x4 acc[WI][4];
    #pragma unroll
    for (int i = 0; i < WI; ++i)
        #pragma unroll
        for (int j = 0; j < 4; ++j) {
            f32x4 z = {0.f, 0.f, 0.f, 0.f};
            acc[i][j] = z;
        }

    for (int k0 = 0; k0 < K; k0 += 32) {
        #pragma unroll
        for (int i = 0; i < WI; ++i) {
            const int s   = tid + i * 256;
            const int row = s >> 3;
            const int c4  = (s & 7) << 2;
            const float4 v = *(const float4*)(A + (long)(m0 + row) * K + k0 + c4);
            if (SPLIT) {
                const __bf16 h0 = (__bf16)v.x, h1 = (__bf16)v.y,
                             h2 = (__bf16)v.z, h3 = (__bf16)v.w;
                bf16x4v hv = {h0, h1, h2, h3};
                *(bf16x4v*)&As_hi[row * LDT + c4] = hv;
                bf16x4v lv = {(__bf16)(v.x - (float)h0), (__bf16)(v.y - (float)h1),
                              (__bf16)(v.z - (float)h2), (__bf16)(v.w - (float)h3)};
                *(bf16x4v*)&As_lo[row * LDT + c4] = lv;
            } else {
                f16x4v hv = {(_Float16)v.x, (_Float16)v.y, (_Float16)v.z, (_Float16)v.w};
                *(f16x4v*)&As_hi[row * LDT + c4] = hv;
            }
        }
        if (BT) {
            #pragma unroll
            for (int i = 0; i < 4; ++i) {
                const int s   = tid + i * 256;
                const int row = s >> 3;
                const int c4  = (s & 7) << 2;
                const float4 v = *(const float4*)(Bm + (long)(n0 + row) * K + k0 + c4);
                if (SPLIT) {
                    const __bf16 h0 = (__bf16)v.x, h1 = (__bf16)v.y,
                                 h2 = (__bf16)v.z, h3 = (__bf16)v.w;
                    bf16x4v hv = {h0, h1, h2, h3};
                    *(bf16x4v*)&Bs_hi[row * LDT + c4] = hv;
                    bf16x4v lv = {(__bf16)(v.x - (float)h0), (__bf16)(v.y - (float)h1),
                                  (__bf16)(v.z - (float)h2), (__bf16)(v.w - (float)h3)};
                    *(bf16x4v*)&Bs_lo[row * LDT + c4] = lv;
                } else {
                    f16x4v hv = {(_Float16)v.x, (_Float16)v.y, (_Float16)v.z, (_Float16)v.w};
                    *(f16x4v*)&Bs_hi[row * LDT + c4] = hv;
                }
            }
        } else {
            const int n  = tid & 127;
            const int kh2 = tid >> 7;
            const float* src = Bm + (long)(k0 + kh2 * 16) * N + n0 + n;
            float xs[16];
            #pragma unroll
            for (int j2 = 0; j2 < 16; ++j2) xs[j2] = src[(long)j2 * N];
            #pragma unroll
            for (int w2 = 0; w2 < 4; ++w2) {
                if (SPLIT) {
                    const __bf16 h0 = (__bf16)xs[w2*4+0], h1 = (__bf16)xs[w2*4+1],
                                 h2 = (__bf16)xs[w2*4+2], h3 = (__bf16)xs[w2*4+3];
                    bf16x4v hv = {h0, h1, h2, h3};
                    *(bf16x4v*)&Bs_hi[n * LDT + kh2 * 16 + w2 * 4] = hv;
                    bf16x4v lv = {(__bf16)(xs[w2*4+0] - (float)h0),
                                  (__bf16)(xs[w2*4+1] - (float)h1),
                                  (__bf16)(xs[w2*4+2] - (float)h2),
                                  (__bf16)(xs[w2*4+3] - (float)h3)};
                    *(bf16x4v*)&Bs_lo[n * LDT + kh2 * 16 + w2 * 4] = lv;
                } else {
                    f16x4v hv = {(_Float16)xs[w2*4+0], (_Float16)xs[w2*4+1],
                                 (_Float16)xs[w2*4+2], (_Float16)xs[w2*4+3]};
                    *(f16x4v*)&Bs_hi[n * LDT + kh2 * 16 + w2 * 4] = hv;
                }
            }
        }
        __syncthreads();

        if (SPLIT) {
            bf16x8 ah[WI], al[WI], bh[4], bl[4];
            #pragma unroll
            for (int i = 0; i < WI; ++i) {
                const int ra = (wm0 + 16 * i + fm) * LDT + fq * 8;
                ah[i] = *(const bf16x8*)&As_hi[ra];
                al[i] = *(const bf16x8*)&As_lo[ra];
            }
            #pragma unroll
            for (int j = 0; j < 4; ++j) {
                const int rb = (wn0 + 16 * j + fm) * LDT + fq * 8;
                bh[j] = *(const bf16x8*)&Bs_hi[rb];
                bl[j] = *(const bf16x8*)&Bs_lo[rb];
            }
            #pragma unroll
            for (int i = 0; i < WI; ++i)
                #pragma unroll
                for (int j = 0; j < 4; ++j) {
                    acc[i][j] = __builtin_amdgcn_mfma_f32_16x16x32_bf16(ah[i], bh[j], acc[i][j], 0, 0, 0);
                    acc[i][j] = __builtin_amdgcn_mfma_f32_16x16x32_bf16(ah[i], bl[j], acc[i][j], 0, 0, 0);
                    acc[i][j] = __builtin_amdgcn_mfma_f32_16x16x32_bf16(al[i], bh[j], acc[i][j], 0, 0, 0);
                }
        } else {
            f16x8 fa[WI], fb[4];
            #pragma unroll
            for (int i = 0; i < WI; ++i)
                fa[i] = *(const f16x8*)&As_hi[(wm0 + 16 * i + fm) * LDT + fq * 8];
            #pragma unroll
            for (int j = 0; j < 4; ++j)
                fb[j] = *(const f16x8*)&Bs_hi[(wn0 + 16 * j + fm) * LDT + fq * 8];
            #pragma unroll
            for (int i = 0; i < WI; ++i)
                #pragma unroll
                for (int j = 0; j < 4; ++j)
                    acc[i][j] = __builtin_amdgcn_mfma_f32_16x16x32_f16(fa[i], fb[j], acc[i][j], 0, 0, 0);
        }
        __syncthreads();
    }

    const float s = SCALE ? scl[0] : 1.0f;
    #pragma unroll
    for (int i = 0; i < WI; ++i) {
        #pragma unroll
        for (int j = 0; j < 4; ++j) {
            const int n = n0 + wn0 + 16 * j + fm;
            float bv = BIAS ? bias[n] : 0.0f;
            #pragma unroll
            for (int r = 0; r < 4; ++r) {
                const int m = m0 + wm0 + 16 * i + fq * 4 + r;
                float v = acc[i][j][r] + bv;
                if (SCALE) v *= s;
                C[(long)m * N + n] = v;
            }
        }
    }
}

extern "C" void kernel_launch(void* const* d_in, const int* in_sizes, int n_in,
                              void* d_out, int out_size, void* d_ws, size_t ws_size,
                              hipStream_t stream) {
    (void)in_sizes; (void)n_in; (void)out_size;

    const float* query = (const float*)d_in[0];
    const float* keys  = (const float*)d_in[1];
    const int*   lens  = (const int*)d_in[2];
    const float* Wq    = (const float*)d_in[3];
    const float* bq    = (const float*)d_in[4];
    const float* scale = (const float*)d_in[5];

    float* out  = (float*)d_out;
    float* ctx  = out;                               // B*TQ*D
    float* attn = out + (size_t)BB * TQ * DD;        // B*TQ*TK

    const size_t NQ  = (size_t)BB * TQ * DD;   // 4,194,304
    const size_t NW  = (size_t)DD * DD;        //   262,144
    const size_t NK  = (size_t)BB * TK * DD;   // 8,388,608
    const size_t NAT = (size_t)BB * TQ * TK;   // 8,388,608
    const size_t REQ = (2 * NQ + NW + 2 * NK + NAT) * 2;  // ~68 MB

    if (ws_size >= REQ) {
        unsigned short* w = (unsigned short*)d_ws;
        unsigned short* q16  = w;               w += NQ;
        unsigned short* w16  = w;               w += NW;
        unsigned short* aq16 = w;               w += NQ;
        unsigned short* k16  = w;               w += NK;
        unsigned short* kT   = w;               w += NK;
        unsigned short* at16 = w;

        // 0a) query+Wq -> fp16
        const int nq4 = (int)(NQ / 4), nw4 = (int)(NW / 4);
        cvt_qw_kernel<<<(nq4 + nw4 + 255) / 256, 256, 0, stream>>>(
            query, Wq, q16, w16, nq4, nw4);
        // 0b) keys -> fp16 + fp16 transposed
        cvt_keys_kernel<<<dim3(TK / 64, DD / 64, BB), 256, 0, stream>>>(
            keys, k16, kT);

        // 1) aq16 = f16gemm(query,Wq) + bq   M=8192 N=512 K=512 (single batch)
        gemm16<64, 2, true, false, 0>
            <<<dim3(DD / 128, (BB * TQ) / 64, 1), 256, 0, stream>>>(
            q16, w16, nullptr, aq16, bq, nullptr, DD, DD, 0, 0, 0);

        // 2) scores = f16gemm(aq, keys) * scale -> attn region (fp32)
        //    XCD-swizzled 1-D grid (512 blocks, 8 n-tiles x 4 m-tiles x 16 b)
        gemm16<128, 0, false, true, 8>
            <<<dim3(512), 256, 0, stream>>>(
            aq16, k16, attn, nullptr, nullptr, scale,
            TK, DD, (long)TQ * DD, (long)TK * DD, (long)TQ * TK);

        // 3) masked softmax in place + fp16 copy
        softmax_kernel<<<BB * TQ, 256, 0, stream>>>(attn, at16, lens);

        // 4) context = f16gemm(attn16, keysT)  M=512 N=512 K=1024 per batch
        //    XCD-swizzled 1-D grid (512 blocks, 4 n-tiles x 8 m-tiles x 16 b)
        gemm16<64, 0, false, false, 4>
            <<<dim3(512), 256, 0, stream>>>(
            at16, kT, ctx, nullptr, nullptr, nullptr,
            DD, TK, (long)TQ * TK, (long)DD * TK, (long)TQ * DD);
    } else {
        // fallback: round-3 path (in-loop conversion)
        float* aq = ctx;
        mfma_gemm<64, false, true, true, false>
            <<<dim3(DD / 128, (BB * TQ) / 64, 1), 256, 0, stream>>>(
            query, Wq, aq, bq, nullptr, DD, DD, 0, 0, 0);
        mfma_gemm<128, true, true, false, true>
            <<<dim3(TK / 128, TQ / 128, BB), 256, 0, stream>>>(
            aq, keys, attn, nullptr, scale, TK, DD,
            (long)TQ * DD, (long)TK * DD, (long)TQ * TK);
        softmax_kernel<<<BB * TQ, 256, 0, stream>>>(attn, nullptr, lens);
        mfma_gemm<64, false, false, false, false>
            <<<dim3(DD / 128, TQ / 64, BB), 256, 0, stream>>>(
            attn, keys, ctx, nullptr, nullptr, DD, TK,
            (long)TQ * TK, (long)TK * DD, (long)TQ * DD);
    }
}

// Round 9
// 163.432 us; speedup vs baseline: 1.2356x; 1.0046x over previous
//
#include <hip/hip_runtime.h>
#include <math.h>

#define BB 16
#define TQ 512
#define TK 1024
#define DD 512

typedef __bf16 bf16x8 __attribute__((ext_vector_type(8)));
typedef __bf16 bf16x4v __attribute__((ext_vector_type(4)));
typedef _Float16 f16x8 __attribute__((ext_vector_type(8)));
typedef _Float16 f16x4v __attribute__((ext_vector_type(4)));
typedef float f32x4 __attribute__((ext_vector_type(4)));

__device__ __forceinline__ unsigned short f16b(float x) {
    _Float16 h = (_Float16)x;
    return __builtin_bit_cast(unsigned short, h);
}

// async global(16B/lane) -> LDS (wave-uniform base + lane*16)
__device__ __forceinline__ void gload16(const void* g, void* l) {
    __builtin_amdgcn_global_load_lds(
        (const __attribute__((address_space(1))) unsigned int*)g,
        (__attribute__((address_space(3))) unsigned int*)l, 16, 0, 0);
}

// ============================================================================
// gemm16: NT GEMM on pre-converted fp16 operands, global_load_lds staging.
//  C[m][n] = sum_k A[m][k]*B[n][k]   OM=0: C fp32.  OM=2: fp16 -> D0.
// Tile TM x 128, 256 thr = 4 waves 2x2, wave tile (TM/2)x64, BK=64.
// LDS unpadded; 16B chunks XOR-swizzled within each 128B row.
// SWZ modes (1-D grid of 512 blocks; xcd = L&7 under round-robin dispatch):
//  SWZ=0: plain dim3 grid.
//  SWZ=1: batched pair map — XCD k hosts batches {2k,2k+1}; 32 tiles/batch,
//         n-tiles = NX. (L2 working set per XCD = 2 batches.)
//  SWZ=2: single-batch (M spans all batches contiguously): XCD k hosts the
//         m-range of batches {2k,2k+1}; 64 slots/xcd = (64/NX) m-tiles x NX.
// ============================================================================
template<int TM, int OM, bool BIAS, bool SCALE, int SWZ, int NX>
__global__ __launch_bounds__(256) void gemm16(
    const unsigned short* __restrict__ A0, const unsigned short* __restrict__ B0,
    float* __restrict__ C, unsigned short* __restrict__ D0,
    const float* __restrict__ bias, const float* __restrict__ scl,
    int N, int K, long sA, long sB, long sC)
{
    constexpr int WI = TM / 32;
    constexpr int IA = TM / 32;
    __shared__ unsigned short As0[TM * 64];
    __shared__ unsigned short Bs0[128 * 64];

    int bz, m0, n0;
    if (SWZ == 1) {
        const int L = blockIdx.x;          // 0..511
        const int xcd = L & 7;
        const int s   = L >> 3;            // 0..63 slot within xcd
        bz = xcd * 2 + (s >> 5);           // 2 batches per xcd
        const int t = s & 31;              // 32 tiles per batch
        n0 = (t % NX) * 128;
        m0 = (t / NX) * TM;
    } else if (SWZ == 2) {
        const int L = blockIdx.x;          // 0..511
        const int xcd = L & 7;
        const int s   = L >> 3;            // 0..63
        bz = 0;
        n0 = (s % NX) * 128;
        const int mt = s / NX;             // 0..(64/NX - 1)
        m0 = (xcd * (64 / NX) + mt) * TM;  // xcd's m-range = 2 batches
    } else {
        bz = blockIdx.z;
        m0 = blockIdx.y * TM;
        n0 = blockIdx.x * 128;
    }

    const long oA = (long)bz * sA, oB = (long)bz * sB;
    const int tid = threadIdx.x, lane = tid & 63, wave = tid >> 6;
    const int wm0 = (wave >> 1) * (TM / 2);
    const int wn0 = (wave & 1) * 64;
    const int fm = lane & 15, fq = lane >> 4;

    f32x4 acc[WI][4];
    #pragma unroll
    for (int i = 0; i < WI; ++i)
        #pragma unroll
        for (int j = 0; j < 4; ++j) {
            f32x4 z = {0.f, 0.f, 0.f, 0.f};
            acc[i][j] = z;
        }

    for (int k0 = 0; k0 < K; k0 += 64) {
        #pragma unroll
        for (int t = 0; t < IA; ++t) {
            const int sb = (wave * IA + t) * 64;
            const int slot = sb + lane;
            const int row = slot >> 3;
            const int g = (slot & 7) ^ (row & 7);
            gload16(A0 + oA + (long)(m0 + row) * K + k0 + g * 8, &As0[sb * 8]);
        }
        #pragma unroll
        for (int t = 0; t < 4; ++t) {
            const int sb = (wave * 4 + t) * 64;
            const int slot = sb + lane;
            const int row = slot >> 3;
            const int g = (slot & 7) ^ (row & 7);
            gload16(B0 + oB + (long)(n0 + row) * K + k0 + g * 8, &Bs0[sb * 8]);
        }
        __syncthreads();

        #pragma unroll
        for (int s = 0; s < 2; ++s) {
            f16x8 fa[WI], fb[4];
            #pragma unroll
            for (int i = 0; i < WI; ++i) {
                const int row = wm0 + 16 * i + fm;
                const int slot = row * 8 + ((s * 4 + fq) ^ (row & 7));
                fa[i] = *(const f16x8*)&As0[slot * 8];
            }
            #pragma unroll
            for (int j = 0; j < 4; ++j) {
                const int row = wn0 + 16 * j + fm;
                const int slot = row * 8 + ((s * 4 + fq) ^ (row & 7));
                fb[j] = *(const f16x8*)&Bs0[slot * 8];
            }
            #pragma unroll
            for (int i = 0; i < WI; ++i)
                #pragma unroll
                for (int j = 0; j < 4; ++j)
                    acc[i][j] = __builtin_amdgcn_mfma_f32_16x16x32_f16(fa[i], fb[j], acc[i][j], 0, 0, 0);
        }
        __syncthreads();
    }

    const float sv = SCALE ? scl[0] : 1.0f;
    #pragma unroll
    for (int i = 0; i < WI; ++i) {
        #pragma unroll
        for (int j = 0; j < 4; ++j) {
            const int n = n0 + wn0 + 16 * j + fm;
            const float bv = BIAS ? bias[n] : 0.0f;
            #pragma unroll
            for (int r = 0; r < 4; ++r) {
                const int m = m0 + wm0 + 16 * i + fq * 4 + r;
                float v = acc[i][j][r] + bv;
                if (SCALE) v *= sv;
                const long o = (long)bz * sC + (long)m * N + n;
                if (OM == 0) C[o] = v;
                else         D0[o] = f16b(v);
            }
        }
    }
}

// query + Wq -> fp16 (float4 per thread)
__global__ __launch_bounds__(256) void cvt_qw_kernel(
    const float* __restrict__ q, const float* __restrict__ w,
    unsigned short* __restrict__ q16, unsigned short* __restrict__ w16,
    int nq4, int nw4)
{
    const int t = blockIdx.x * 256 + threadIdx.x;
    const float* s;
    unsigned short* d;
    if (t < nq4)            { s = q + (long)t * 4;         d = q16 + (long)t * 4; }
    else if (t < nq4 + nw4) { s = w + (long)(t - nq4) * 4; d = w16 + (long)(t - nq4) * 4; }
    else return;
    const float4 v = *(const float4*)s;
    f16x4v o = {(_Float16)v.x, (_Float16)v.y, (_Float16)v.z, (_Float16)v.w};
    *(f16x4v*)d = o;
}

// keys -> fp16 row-major [b][k][d] + fp16 transposed [b][d][k], 64x64 tiles
__global__ __launch_bounds__(256) void cvt_keys_kernel(
    const float* __restrict__ keys, unsigned short* __restrict__ k16,
    unsigned short* __restrict__ kT)
{
    __shared__ unsigned short T[64][72];
    const int b = blockIdx.z, kt = blockIdx.x, dt = blockIdx.y;
    const int tid = threadIdx.x;
    const float* src = keys + ((long)b * TK + (long)kt * 64) * DD + dt * 64;

    #pragma unroll
    for (int i = 0; i < 4; ++i) {
        const int slot = tid + i * 256;
        const int r  = slot >> 4;
        const int c4 = (slot & 15) * 4;
        const float4 v = *(const float4*)(src + (long)r * DD + c4);
        const unsigned short h0 = f16b(v.x), h1 = f16b(v.y),
                             h2 = f16b(v.z), h3 = f16b(v.w);
        *(ushort4*)&k16[((long)b * TK + kt * 64 + r) * DD + dt * 64 + c4] =
            make_ushort4(h0, h1, h2, h3);
        T[c4 + 0][r] = h0;
        T[c4 + 1][r] = h1;
        T[c4 + 2][r] = h2;
        T[c4 + 3][r] = h3;
    }
    __syncthreads();
    #pragma unroll
    for (int i = 0; i < 4; ++i) {
        const int slot = tid + i * 256;
        const int c  = slot >> 4;
        const int r4 = (slot & 15) * 4;
        const ushort4 o4 = *(const ushort4*)&T[c][r4];
        *(ushort4*)&kT[((long)b * DD + dt * 64 + c) * TK + kt * 64 + r4] = o4;
    }
}

// ============================================================================
// Masked softmax: one row per WAVE (64 lanes x 16 f32), no LDS, no barriers.
// 2048 blocks x 4 waves, XCD-aligned: XCD k handles batches {2k,2k+1} so the
// scores read (written by gemm2 on the same XCD) and the at16 write (read by
// gemm3 on the same XCD) stay in the local 4MB L2.
// ============================================================================
__global__ __launch_bounds__(256) void softmax_kernel(
    float* __restrict__ attn, unsigned short* __restrict__ attn16,
    const int* __restrict__ lens)
{
    const int L   = blockIdx.x;            // 0..2047
    const int xcd = L & 7;
    const int s   = L >> 3;                // 0..255
    const int b   = xcd * 2 + (s >> 7);    // batch
    const int rloc = (s & 127) * 4 + (threadIdx.x >> 6);
    const int row  = b * TQ + rloc;
    const int lane = threadIdx.x & 63;
    const int len  = lens[b];

    float* p = attn + (long)row * TK;
    float x[16];
    float mx = -INFINITY;
    #pragma unroll
    for (int i = 0; i < 4; ++i) {
        const int c0 = i * 256 + lane * 4;
        const float4 v = *(const float4*)(p + c0);
        x[i * 4 + 0] = v.x; x[i * 4 + 1] = v.y;
        x[i * 4 + 2] = v.z; x[i * 4 + 3] = v.w;
        #pragma unroll
        for (int j = 0; j < 4; ++j) {
            if (c0 + j < len) mx = fmaxf(mx, x[i * 4 + j]);
            else x[i * 4 + j] = -INFINITY;
        }
    }
    #pragma unroll
    for (int off = 32; off; off >>= 1) mx = fmaxf(mx, __shfl_xor(mx, off, 64));

    float sum = 0.0f;
    #pragma unroll
    for (int i = 0; i < 16; ++i) {
        const float e = (x[i] > -INFINITY) ? __expf(x[i] - mx) : 0.0f;
        x[i] = e;
        sum += e;
    }
    #pragma unroll
    for (int off = 32; off; off >>= 1) sum += __shfl_xor(sum, off, 64);

    const float inv = 1.0f / sum;
    unsigned short* q = attn16 + (long)row * TK;
    #pragma unroll
    for (int i = 0; i < 4; ++i) {
        const int c0 = i * 256 + lane * 4;
        const float o0 = x[i * 4 + 0] * inv, o1 = x[i * 4 + 1] * inv,
                    o2 = x[i * 4 + 2] * inv, o3 = x[i * 4 + 3] * inv;
        float4 o = {o0, o1, o2, o3};
        *(float4*)(p + c0) = o;
        f16x4v o16 = {(_Float16)o0, (_Float16)o1, (_Float16)o2, (_Float16)o3};
        *(f16x4v*)(q + c0) = o16;
    }
}

// ============================================================================
// FALLBACK PATH: fp32-input MFMA GEMM with in-loop conversion (round-3 proven).
// ============================================================================
template<int TM, bool SPLIT, bool BT, bool BIAS, bool SCALE>
__global__ __launch_bounds__(256) void mfma_gemm(
    const float* __restrict__ A, const float* __restrict__ Bm,
    float* __restrict__ C, const float* __restrict__ bias,
    const float* __restrict__ scl,
    int N, int K, long sA, long sB, long sC)
{
    constexpr int WI  = TM / 32;
    constexpr int LDT = 40;
    __shared__ unsigned short As_hi[TM * LDT];
    __shared__ unsigned short Bs_hi[128 * LDT];
    __shared__ unsigned short As_lo[SPLIT ? TM * LDT : 8];
    __shared__ unsigned short Bs_lo[SPLIT ? 128 * LDT : 8];

    const int bz = blockIdx.z;
    A  += (long)bz * sA;
    Bm += (long)bz * sB;
    C  += (long)bz * sC;

    const int m0 = blockIdx.y * TM;
    const int n0 = blockIdx.x * 128;
    const int tid  = threadIdx.x;
    const int lane = tid & 63;
    const int wave = tid >> 6;
    const int wm0 = (wave >> 1) * (TM / 2);
    const int wn0 = (wave & 1) * 64;
    const int fm = lane & 15;
    const int fq = lane >> 4;

    f32x4 acc[WI][4];
    #pragma unroll
    for (int i = 0; i < WI; ++i)
        #pragma unroll
        for (int j = 0; j < 4; ++j) {
            f32x4 z = {0.f, 0.f, 0.f, 0.f};
            acc[i][j] = z;
        }

    for (int k0 = 0; k0 < K; k0 += 32) {
        #pragma unroll
        for (int i = 0; i < WI; ++i) {
            const int s   = tid + i * 256;
            const int row = s >> 3;
            const int c4  = (s & 7) << 2;
            const float4 v = *(const float4*)(A + (long)(m0 + row) * K + k0 + c4);
            if (SPLIT) {
                const __bf16 h0 = (__bf16)v.x, h1 = (__bf16)v.y,
                             h2 = (__bf16)v.z, h3 = (__bf16)v.w;
                bf16x4v hv = {h0, h1, h2, h3};
                *(bf16x4v*)&As_hi[row * LDT + c4] = hv;
                bf16x4v lv = {(__bf16)(v.x - (float)h0), (__bf16)(v.y - (float)h1),
                              (__bf16)(v.z - (float)h2), (__bf16)(v.w - (float)h3)};
                *(bf16x4v*)&As_lo[row * LDT + c4] = lv;
            } else {
                f16x4v hv = {(_Float16)v.x, (_Float16)v.y, (_Float16)v.z, (_Float16)v.w};
                *(f16x4v*)&As_hi[row * LDT + c4] = hv;
            }
        }
        if (BT) {
            #pragma unroll
            for (int i = 0; i < 4; ++i) {
                const int s   = tid + i * 256;
                const int row = s >> 3;
                const int c4  = (s & 7) << 2;
                const float4 v = *(const float4*)(Bm + (long)(n0 + row) * K + k0 + c4);
                if (SPLIT) {
                    const __bf16 h0 = (__bf16)v.x, h1 = (__bf16)v.y,
                                 h2 = (__bf16)v.z, h3 = (__bf16)v.w;
                    bf16x4v hv = {h0, h1, h2, h3};
                    *(bf16x4v*)&Bs_hi[row * LDT + c4] = hv;
                    bf16x4v lv = {(__bf16)(v.x - (float)h0), (__bf16)(v.y - (float)h1),
                                  (__bf16)(v.z - (float)h2), (__bf16)(v.w - (float)h3)};
                    *(bf16x4v*)&Bs_lo[row * LDT + c4] = lv;
                } else {
                    f16x4v hv = {(_Float16)v.x, (_Float16)v.y, (_Float16)v.z, (_Float16)v.w};
                    *(f16x4v*)&Bs_hi[row * LDT + c4] = hv;
                }
            }
        } else {
            const int n  = tid & 127;
            const int kh2 = tid >> 7;
            const float* src = Bm + (long)(k0 + kh2 * 16) * N + n0 + n;
            float xs[16];
            #pragma unroll
            for (int j2 = 0; j2 < 16; ++j2) xs[j2] = src[(long)j2 * N];
            #pragma unroll
            for (int w2 = 0; w2 < 4; ++w2) {
                if (SPLIT) {
                    const __bf16 h0 = (__bf16)xs[w2*4+0], h1 = (__bf16)xs[w2*4+1],
                                 h2 = (__bf16)xs[w2*4+2], h3 = (__bf16)xs[w2*4+3];
                    bf16x4v hv = {h0, h1, h2, h3};
                    *(bf16x4v*)&Bs_hi[n * LDT + kh2 * 16 + w2 * 4] = hv;
                    bf16x4v lv = {(__bf16)(xs[w2*4+0] - (float)h0),
                                  (__bf16)(xs[w2*4+1] - (float)h1),
                                  (__bf16)(xs[w2*4+2] - (float)h2),
                                  (__bf16)(xs[w2*4+3] - (float)h3)};
                    *(bf16x4v*)&Bs_lo[n * LDT + kh2 * 16 + w2 * 4] = lv;
                } else {
                    f16x4v hv = {(_Float16)xs[w2*4+0], (_Float16)xs[w2*4+1],
                                 (_Float16)xs[w2*4+2], (_Float16)xs[w2*4+3]};
                    *(f16x4v*)&Bs_hi[n * LDT + kh2 * 16 + w2 * 4] = hv;
                }
            }
        }
        __syncthreads();

        if (SPLIT) {
            bf16x8 ah[WI], al[WI], bh[4], bl[4];
            #pragma unroll
            for (int i = 0; i < WI; ++i) {
                const int ra = (wm0 + 16 * i + fm) * LDT + fq * 8;
                ah[i] = *(const bf16x8*)&As_hi[ra];
                al[i] = *(const bf16x8*)&As_lo[ra];
            }
            #pragma unroll
            for (int j = 0; j < 4; ++j) {
                const int rb = (wn0 + 16 * j + fm) * LDT + fq * 8;
                bh[j] = *(const bf16x8*)&Bs_hi[rb];
                bl[j] = *(const bf16x8*)&Bs_lo[rb];
            }
            #pragma unroll
            for (int i = 0; i < WI; ++i)
                #pragma unroll
                for (int j = 0; j < 4; ++j) {
                    acc[i][j] = __builtin_amdgcn_mfma_f32_16x16x32_bf16(ah[i], bh[j], acc[i][j], 0, 0, 0);
                    acc[i][j] = __builtin_amdgcn_mfma_f32_16x16x32_bf16(ah[i], bl[j], acc[i][j], 0, 0, 0);
                    acc[i][j] = __builtin_amdgcn_mfma_f32_16x16x32_bf16(al[i], bh[j], acc[i][j], 0, 0, 0);
                }
        } else {
            f16x8 fa[WI], fb[4];
            #pragma unroll
            for (int i = 0; i < WI; ++i)
                fa[i] = *(const f16x8*)&As_hi[(wm0 + 16 * i + fm) * LDT + fq * 8];
            #pragma unroll
            for (int j = 0; j < 4; ++j)
                fb[j] = *(const f16x8*)&Bs_hi[(wn0 + 16 * j + fm) * LDT + fq * 8];
            #pragma unroll
            for (int i = 0; i < WI; ++i)
                #pragma unroll
                for (int j = 0; j < 4; ++j)
                    acc[i][j] = __builtin_amdgcn_mfma_f32_16x16x32_f16(fa[i], fb[j], acc[i][j], 0, 0, 0);
        }
        __syncthreads();
    }

    const float s = SCALE ? scl[0] : 1.0f;
    #pragma unroll
    for (int i = 0; i < WI; ++i) {
        #pragma unroll
        for (int j = 0; j < 4; ++j) {
            const int n = n0 + wn0 + 16 * j + fm;
            float bv = BIAS ? bias[n] : 0.0f;
            #pragma unroll
            for (int r = 0; r < 4; ++r) {
                const int m = m0 + wm0 + 16 * i + fq * 4 + r;
                float v = acc[i][j][r] + bv;
                if (SCALE) v *= s;
                C[(long)m * N + n] = v;
            }
        }
    }
}

// Masked softmax (fallback path), one block per (b,q) row.
__global__ __launch_bounds__(256) void softmax_fb_kernel(
    float* __restrict__ attn, const int* __restrict__ lens)
{
    const int row = blockIdx.x;
    const int b   = row >> 9;
    const int len = lens[b];
    float* p = attn + (long)row * TK;

    const int tid  = threadIdx.x;
    const int lane = tid & 63;
    const int wave = tid >> 6;
    const int k0   = tid * 4;

    const float4 v = *(const float4*)(p + k0);
    float x[4] = {v.x, v.y, v.z, v.w};
    float mx = -INFINITY;
    #pragma unroll
    for (int i = 0; i < 4; ++i) {
        if (k0 + i < len) mx = fmaxf(mx, x[i]);
        else x[i] = -INFINITY;
    }
    #pragma unroll
    for (int off = 32; off; off >>= 1) mx = fmaxf(mx, __shfl_xor(mx, off, 64));

    __shared__ float red[8];
    if (lane == 0) red[wave] = mx;
    __syncthreads();
    mx = fmaxf(fmaxf(red[0], red[1]), fmaxf(red[2], red[3]));

    float e[4];
    float sum = 0.0f;
    #pragma unroll
    for (int i = 0; i < 4; ++i) {
        e[i] = (x[i] > -INFINITY) ? __expf(x[i] - mx) : 0.0f;
        sum += e[i];
    }
    #pragma unroll
    for (int off = 32; off; off >>= 1) sum += __shfl_xor(sum, off, 64);
    if (lane == 0) red[4 + wave] = sum;
    __syncthreads();
    sum = red[4] + red[5] + red[6] + red[7];

    const float inv = 1.0f / sum;
    float4 o = {e[0] * inv, e[1] * inv, e[2] * inv, e[3] * inv};
    *(float4*)(p + k0) = o;
}

extern "C" void kernel_launch(void* const* d_in, const int* in_sizes, int n_in,
                              void* d_out, int out_size, void* d_ws, size_t ws_size,
                              hipStream_t stream) {
    (void)in_sizes; (void)n_in; (void)out_size;

    const float* query = (const float*)d_in[0];
    const float* keys  = (const float*)d_in[1];
    const int*   lens  = (const int*)d_in[2];
    const float* Wq    = (const float*)d_in[3];
    const float* bq    = (const float*)d_in[4];
    const float* scale = (const float*)d_in[5];

    float* out  = (float*)d_out;
    float* ctx  = out;                               // B*TQ*D
    float* attn = out + (size_t)BB * TQ * DD;        // B*TQ*TK

    const size_t NQ  = (size_t)BB * TQ * DD;   // 4,194,304
    const size_t NW  = (size_t)DD * DD;        //   262,144
    const size_t NK  = (size_t)BB * TK * DD;   // 8,388,608
    const size_t NAT = (size_t)BB * TQ * TK;   // 8,388,608
    const size_t REQ = (2 * NQ + NW + 2 * NK + NAT) * 2;  // ~68 MB

    if (ws_size >= REQ) {
        unsigned short* w = (unsigned short*)d_ws;
        unsigned short* q16  = w;               w += NQ;
        unsigned short* w16  = w;               w += NW;
        unsigned short* aq16 = w;               w += NQ;
        unsigned short* k16  = w;               w += NK;
        unsigned short* kT   = w;               w += NK;
        unsigned short* at16 = w;

        // 0a) query+Wq -> fp16
        const int nq4 = (int)(NQ / 4), nw4 = (int)(NW / 4);
        cvt_qw_kernel<<<(nq4 + nw4 + 255) / 256, 256, 0, stream>>>(
            query, Wq, q16, w16, nq4, nw4);
        // 0b) keys -> fp16 + fp16 transposed
        cvt_keys_kernel<<<dim3(TK / 64, DD / 64, BB), 256, 0, stream>>>(
            keys, k16, kT);

        // 1) aq16 = f16gemm(query,Wq) + bq   M=8192 N=512 K=512
        //    XCD-aligned: XCD k computes rows of batches {2k,2k+1}
        gemm16<64, 2, true, false, 2, 4>
            <<<dim3(512), 256, 0, stream>>>(
            q16, w16, nullptr, aq16, bq, nullptr, DD, DD, 0, 0, 0);

        // 2) scores = f16gemm(aq, keys) * scale -> attn region (fp32)
        //    XCD-aligned batched (8 n-tiles x 4 m-tiles x 16 b)
        gemm16<128, 0, false, true, 1, 8>
            <<<dim3(512), 256, 0, stream>>>(
            aq16, k16, attn, nullptr, nullptr, scale,
            TK, DD, (long)TQ * DD, (long)TK * DD, (long)TQ * TK);

        // 3) masked softmax in place + fp16 copy (wave-per-row, XCD-aligned)
        softmax_kernel<<<dim3(2048), 256, 0, stream>>>(attn, at16, lens);

        // 4) context = f16gemm(attn16, keysT)  M=512 N=512 K=1024 per batch
        //    XCD-aligned batched (4 n-tiles x 8 m-tiles x 16 b)
        gemm16<64, 0, false, false, 1, 4>
            <<<dim3(512), 256, 0, stream>>>(
            at16, kT, ctx, nullptr, nullptr, nullptr,
            DD, TK, (long)TQ * TK, (long)DD * TK, (long)TQ * DD);
    } else {
        // fallback: round-3 path (in-loop conversion)
        float* aq = ctx;
        mfma_gemm<64, false, true, true, false>
            <<<dim3(DD / 128, (BB * TQ) / 64, 1), 256, 0, stream>>>(
            query, Wq, aq, bq, nullptr, DD, DD, 0, 0, 0);
        mfma_gemm<128, true, true, false, true>
            <<<dim3(TK / 128, TQ / 128, BB), 256, 0, stream>>>(
            aq, keys, attn, nullptr, scale, TK, DD,
            (long)TQ * DD, (long)TK * DD, (long)TQ * TK);
        softmax_fb_kernel<<<BB * TQ, 256, 0, stream>>>(attn, lens);
        mfma_gemm<64, false, false, false, false>
            <<<dim3(DD / 128, TQ / 64, BB), 256, 0, stream>>>(
            attn, keys, ctx, nullptr, nullptr, DD, TK,
            (long)TQ * TK, (long)TK * DD, (long)TQ * DD);
    }
}